// Round 12
// baseline (49.522 us; speedup 1.0000x reference)
//
#include <hip/hip_runtime.h>

// out[b,n] = softmax-gated mix of 4 activations of s[b,n], gates from a
// per-neuron 4->4->4 MLP (W1,b1,W2,b2). All f32.
// PACKING FLIPPED vs R6-R11: thread owns TWO ADJACENT NEURONS (2g, 2g+1);
// each v2f = {elem of neuron 2g, elem of neuron 2g+1} for one batch row.
// -> every v_pk_* operand carries genuine per-neuron data (no splat movs,
//    no broadcast register waste), weight pairs load once from adjacent
//    memory, and s/out accesses are contiguous 8B vector ops (half the
//    addressing, perfect coalescing).
// Row loop: R8-proven rolled depth-1 prefetch, ping-pong named buffers.
// Math identical to R6-R11: Pade(7,6) rational sigmoids (1 shared rcp per
// 4 hidden units), softmax in log2 domain shifted by l3 (3 exps/elem).

typedef float v2f __attribute__((ext_vector_type(2)));
#define SPL(x) ((v2f)(x))

static __device__ __forceinline__ v2f fma2(v2f a, v2f b, v2f c) {
    return __builtin_elementwise_fma(a, b, c);
}
static __device__ __forceinline__ v2f exp2v(v2f y) {
    v2f r; r.x = __builtin_amdgcn_exp2f(y.x); r.y = __builtin_amdgcn_exp2f(y.y); return r;
}
static __device__ __forceinline__ v2f rcpv(v2f d) {
    v2f r; r.x = __builtin_amdgcn_rcpf(d.x); r.y = __builtin_amdgcn_rcpf(d.y); return r;
}

__global__ __launch_bounds__(256) void gatemix_kernel(
    const float* __restrict__ s,
    const float* __restrict__ W1,
    const float* __restrict__ b1,
    const float* __restrict__ W2,
    const float* __restrict__ b2,
    float* __restrict__ out,
    int B, int N)
{
    const int g  = blockIdx.x * 256 + threadIdx.x;   // neuron-PAIR index
    const int n0 = 2 * g;                            // first neuron of pair
    const float L2E = 1.44269504088896340736f;

    // Per-neuron-pair params: w1[k][j] = {W1[n0,k,j], W1[n0+1,k,j]} etc.
    // Loaded as float4 rows (adjacent in memory), interleaved into pairs.
    // W2/b2 pre-scaled by log2(e) so logits land in log2 domain.
    const float4* W1v = (const float4*)W1;
    const float4* W2v = (const float4*)W2;
    v2f w1[4][4], w2[4][4], bb1[4], bb2[4];
    #pragma unroll
    for (int k = 0; k < 4; ++k) {
        float4 ra = W1v[(size_t)n0*4 + k];          // W1[n0,  k, :]
        float4 rb = W1v[(size_t)n0*4 + 4 + k];      // W1[n0+1,k, :]
        w1[k][0] = (v2f){ra.x, rb.x};
        w1[k][1] = (v2f){ra.y, rb.y};
        w1[k][2] = (v2f){ra.z, rb.z};
        w1[k][3] = (v2f){ra.w, rb.w};
    }
    #pragma unroll
    for (int j = 0; j < 4; ++j) {
        float4 ra = W2v[(size_t)n0*4 + j];          // W2[n0,  j, :]
        float4 rb = W2v[(size_t)n0*4 + 4 + j];      // W2[n0+1,j, :]
        w2[j][0] = (v2f){ra.x*L2E, rb.x*L2E};
        w2[j][1] = (v2f){ra.y*L2E, rb.y*L2E};
        w2[j][2] = (v2f){ra.z*L2E, rb.z*L2E};
        w2[j][3] = (v2f){ra.w*L2E, rb.w*L2E};
    }
    {
        float4 ba = ((const float4*)b1)[n0];
        float4 bbq = ((const float4*)b1)[n0+1];
        bb1[0] = (v2f){ba.x, bbq.x};
        bb1[1] = (v2f){ba.y, bbq.y};
        bb1[2] = (v2f){ba.z, bbq.z};
        bb1[3] = (v2f){ba.w, bbq.w};
        float4 ca = ((const float4*)b2)[n0];
        float4 cb = ((const float4*)b2)[n0+1];
        bb2[0] = (v2f){ca.x*L2E, cb.x*L2E};
        bb2[1] = (v2f){ca.y*L2E, cb.y*L2E};
        bb2[2] = (v2f){ca.z*L2E, cb.z*L2E};
        bb2[3] = (v2f){ca.w*L2E, cb.w*L2E};
    }

    // sigmoid(z) = 0.5 + z*Np(z*z)*rcp(Dp(z*z)), Pade(7,6) of tanh(z/2).
    const v2f cn1 = SPL(8.0128205e-3f), cn2 = SPL(4.3706294e-5f), cn3 = SPL(2.8906051e-8f);
    const v2f cd1 = SPL(1.1538462e-1f), cd2 = SPL(1.4568765e-3f), cd3 = SPL(3.2372594e-6f);
    const v2f vQ = SPL(0.25f), vH = SPL(0.5f), vOne = SPL(1.0f);

    const int BCHUNK = 16;
    const size_t sN = (size_t)N;
    const float* sp = s   + (size_t)(blockIdx.y * BCHUNK) * sN + n0;
    float*       op = out + (size_t)(blockIdx.y * BCHUNK) * sN + n0;

    // load rows r, r+1 (each one contiguous 8B v2f covering both neurons)
    auto load2 = [&](int r, v2f& x0, v2f& x1) {
        x0 = *(const v2f*)(sp + (size_t)r     * sN);
        x1 = *(const v2f*)(sp + (size_t)(r+1) * sN);
    };

    // compute rows r, r+1 as two independent chains (ILP=2)
    auto compute2 = [&](int r, v2f x0, v2f x1) {
        v2f x[2] = {x0, x1};
        v2f a0[2], a1[2], a2[2];
        #pragma unroll
        for (int c = 0; c < 2; ++c) {
            a0[c] = __builtin_elementwise_max(x[c], SPL(0.0f));
            a2[c] = __builtin_elementwise_min(x[c], SPL(0.0f));
            v2f u  = x[c] * x[c];
            v2f pn = fma2(fma2(fma2(cn3, u, cn2), u, cn1), u, vQ);
            v2f pd = fma2(fma2(fma2(cd3, u, cd2), u, cd1), u, vOne);
            a1[c]  = fma2(x[c] * pn, rcpv(pd), vH);
        }

        v2f h[2][4];
        #pragma unroll
        for (int c = 0; c < 2; ++c) {
            v2f qd[4], nm[4];
            #pragma unroll
            for (int j = 0; j < 4; ++j) {
                v2f zj = fma2(a0[c], w1[0][j],
                         fma2(a1[c], w1[1][j],
                         fma2(a2[c], w1[2][j],
                         fma2(x[c],  w1[3][j], bb1[j]))));
                v2f vv = zj * zj;
                v2f nn = fma2(fma2(fma2(cn3, vv, cn2), vv, cn1), vv, vQ);
                qd[j]  = fma2(fma2(fma2(cd3, vv, cd2), vv, cd1), vv, vOne);
                nm[j]  = zj * nn;
            }
            // one rcp for all 4 hidden sigmoids
            v2f p01 = qd[0] * qd[1];
            v2f p23 = qd[2] * qd[3];
            v2f rr  = rcpv(p01 * p23);
            v2f i01 = p23 * rr;              // 1/(qd0*qd1)
            v2f i23 = p01 * rr;              // 1/(qd2*qd3)
            h[c][0] = fma2(nm[0] * qd[1], i01, vH);
            h[c][1] = fma2(nm[1] * qd[0], i01, vH);
            h[c][2] = fma2(nm[2] * qd[3], i23, vH);
            h[c][3] = fma2(nm[3] * qd[2], i23, vH);
        }

        #pragma unroll
        for (int c = 0; c < 2; ++c) {
            v2f l0 = fma2(h[c][0],w2[0][0], fma2(h[c][1],w2[1][0], fma2(h[c][2],w2[2][0], fma2(h[c][3],w2[3][0], bb2[0]))));
            v2f l1 = fma2(h[c][0],w2[0][1], fma2(h[c][1],w2[1][1], fma2(h[c][2],w2[2][1], fma2(h[c][3],w2[3][1], bb2[1]))));
            v2f l2 = fma2(h[c][0],w2[0][2], fma2(h[c][1],w2[1][2], fma2(h[c][2],w2[2][2], fma2(h[c][3],w2[3][2], bb2[2]))));
            v2f l3 = fma2(h[c][0],w2[0][3], fma2(h[c][1],w2[1][3], fma2(h[c][2],w2[2][3], fma2(h[c][3],w2[3][3], bb2[3]))));
            // softmax shifted by l3 (e3 == 1), log2 domain
            v2f e0 = exp2v(l0 - l3);
            v2f e1 = exp2v(l1 - l3);
            v2f e2 = exp2v(l2 - l3);
            v2f den = (e0 + e1) + (e2 + vOne);
            v2f num = fma2(e0, a0[c], fma2(e1, a1[c], fma2(e2, a2[c], x[c])));
            v2f o = num * rcpv(den);
            *(v2f*)(op + (size_t)(r + c) * sN) = o;   // contiguous 8B store
        }
    };

    // Depth-1 software pipeline, two named buffers, rolled loop (8x2 rows).
    v2f xA0, xA1, xB0, xB1;
    load2(0, xA0, xA1);
    #pragma unroll 1
    for (int it = 0; it < 8; it += 2) {
        load2((it+1)*2, xB0, xB1);           // prefetch next row-pair
        compute2(it*2, xA0, xA1);
        if (it + 2 < 8)
            load2((it+2)*2, xA0, xA1);       // prefetch into freed buffer
        compute2((it+1)*2, xB0, xB1);
    }
}

extern "C" void kernel_launch(void* const* d_in, const int* in_sizes, int n_in,
                              void* d_out, int out_size, void* d_ws, size_t ws_size,
                              hipStream_t stream) {
    const float* s  = (const float*)d_in[0];
    const float* W1 = (const float*)d_in[1];
    const float* b1 = (const float*)d_in[2];
    const float* W2 = (const float*)d_in[3];
    const float* b2 = (const float*)d_in[4];
    float* out = (float*)d_out;

    const int K = 4;
    const int N = in_sizes[2] / K;       // b1 is N*K
    const int B = in_sizes[0] / N;       // s is B*N

    dim3 grid(N / 512, B / 16);          // 256 threads x 2 neurons = 512
    gatemix_kernel<<<grid, 256, 0, stream>>>(s, W1, b1, W2, b2, out, B, N);
}

// Round 13
// 45.718 us; speedup vs baseline: 1.0832x; 1.0832x over previous
//
#include <hip/hip_runtime.h>

// out[b,n] = softmax-gated mix of 4 activations of s[b,n], gates from a
// per-neuron 4->4->4 MLP (W1,b1,W2,b2). All f32.
// Thread owns neuron n (splat v2f params -- compiler broadcasts via VOP3P
// op_sel, 1 VGPR per scalar; R12 proved distinct-pair layout spills to
// cache reloads). BCHUNK=8 rows, all preloaded (4 v2f). ILP=1 single chain
// per iter; latency hiding comes from occupancy: total VGPR budget aimed
// UNDER the 64-reg step (waves/SIMD double at <=64). W2/b2 pre-differenced
// (lam_k = l_k - l_3) and pre-scaled by log2e: -5 regs, -7 instrs/iter.
// Pade(7,6) rational sigmoids (1 shared rcp per 4 hidden units), softmax
// via 3 exp2 on difference logits.

typedef float v2f __attribute__((ext_vector_type(2)));
#define SPL(x) ((v2f)(x))

static __device__ __forceinline__ v2f fma2(v2f a, v2f b, v2f c) {
    return __builtin_elementwise_fma(a, b, c);
}
static __device__ __forceinline__ v2f exp2v(v2f y) {
    v2f r; r.x = __builtin_amdgcn_exp2f(y.x); r.y = __builtin_amdgcn_exp2f(y.y); return r;
}
static __device__ __forceinline__ v2f rcpv(v2f d) {
    v2f r; r.x = __builtin_amdgcn_rcpf(d.x); r.y = __builtin_amdgcn_rcpf(d.y); return r;
}

__global__ __launch_bounds__(256) void gatemix_kernel(
    const float* __restrict__ s,
    const float* __restrict__ W1,
    const float* __restrict__ b1,
    const float* __restrict__ W2,
    const float* __restrict__ b2,
    float* __restrict__ out,
    int B, int N)
{
    const int n = blockIdx.x * 256 + threadIdx.x;
    const float L2E = 1.44269504088896340736f;

    // Splat params (1 VGPR each via compiler op_sel broadcast).
    const float4* W1v = (const float4*)W1;
    const float4* W2v = (const float4*)W2;
    v2f w1[4][4], bb1[4];
    #pragma unroll
    for (int k = 0; k < 4; ++k) {
        float4 rw = W1v[(size_t)n*4 + k];                    // W1[n,k,:]
        w1[k][0] = SPL(rw.x); w1[k][1] = SPL(rw.y);
        w1[k][2] = SPL(rw.z); w1[k][3] = SPL(rw.w);
    }
    {
        float4 rb = ((const float4*)b1)[n];
        bb1[0]=SPL(rb.x); bb1[1]=SPL(rb.y); bb1[2]=SPL(rb.z); bb1[3]=SPL(rb.w);
    }
    // Difference logits: lam_k = l_k - l_3 (k=0..2), log2 domain.
    v2f w2d[4][3], bb2[3];
    #pragma unroll
    for (int j = 0; j < 4; ++j) {
        float4 rw = W2v[(size_t)n*4 + j];                    // W2[n,j,:]
        w2d[j][0] = SPL((rw.x - rw.w) * L2E);
        w2d[j][1] = SPL((rw.y - rw.w) * L2E);
        w2d[j][2] = SPL((rw.z - rw.w) * L2E);
    }
    {
        float4 rc = ((const float4*)b2)[n];
        bb2[0] = SPL((rc.x - rc.w) * L2E);
        bb2[1] = SPL((rc.y - rc.w) * L2E);
        bb2[2] = SPL((rc.z - rc.w) * L2E);
    }

    // sigmoid(z) = 0.5 + z*Np(z*z)*rcp(Dp(z*z)), Pade(7,6) of tanh(z/2).
    const v2f cn1 = SPL(8.0128205e-3f), cn2 = SPL(4.3706294e-5f), cn3 = SPL(2.8906051e-8f);
    const v2f cd1 = SPL(1.1538462e-1f), cd2 = SPL(1.4568765e-3f), cd3 = SPL(3.2372594e-6f);
    const v2f vQ = SPL(0.25f), vH = SPL(0.5f), vOne = SPL(1.0f);

    const int BCHUNK = 8;
    const size_t sN = (size_t)N;
    const float* sp = s   + (size_t)(blockIdx.y * BCHUNK) * sN + n;
    float*       op = out + (size_t)(blockIdx.y * BCHUNK) * sN + n;

    // Preload all 8 rows (4 v2f, 8 outstanding loads; in-order vmcnt means
    // iter k waits only on its own 2 loads, rest stay in flight).
    v2f xr[4];
    #pragma unroll
    for (int r = 0; r < 4; ++r) {
        xr[r].x = sp[(size_t)(2*r)   * sN];
        xr[r].y = sp[(size_t)(2*r+1) * sN];
    }

    #pragma unroll
    for (int it = 0; it < 4; ++it) {
        const v2f x = xr[it];

        // acts: relu, antirelu (identity = x); a1 = sigmoid(x) rational
        v2f a0 = __builtin_elementwise_max(x, SPL(0.0f));
        v2f a2 = __builtin_elementwise_min(x, SPL(0.0f));
        v2f u  = x * x;
        v2f pn = fma2(fma2(fma2(cn3, u, cn2), u, cn1), u, vQ);
        v2f pd = fma2(fma2(fma2(cd3, u, cd2), u, cd1), u, vOne);
        v2f a1 = fma2(x * pn, rcpv(pd), vH);

        // hidden pre-activations + rational pieces
        v2f qd[4], nm[4];
        #pragma unroll
        for (int j = 0; j < 4; ++j) {
            v2f zj = fma2(a0, w1[0][j],
                     fma2(a1, w1[1][j],
                     fma2(a2, w1[2][j],
                     fma2(x,  w1[3][j], bb1[j]))));
            v2f vv = zj * zj;
            v2f nn = fma2(fma2(fma2(cn3, vv, cn2), vv, cn1), vv, vQ);
            qd[j]  = fma2(fma2(fma2(cd3, vv, cd2), vv, cd1), vv, vOne);
            nm[j]  = zj * nn;
        }
        // one rcp for all 4 hidden sigmoids
        v2f p01 = qd[0] * qd[1];
        v2f p23 = qd[2] * qd[3];
        v2f rr  = rcpv(p01 * p23);
        v2f i01 = p23 * rr;                  // 1/(qd0*qd1)
        v2f i23 = p01 * rr;                  // 1/(qd2*qd3)
        v2f h0 = fma2(nm[0] * qd[1], i01, vH);
        v2f h1 = fma2(nm[1] * qd[0], i01, vH);
        v2f h2 = fma2(nm[2] * qd[3], i23, vH);
        v2f h3 = fma2(nm[3] * qd[2], i23, vH);

        // difference logits (log2 domain) -> 3 exps
        v2f l0 = fma2(h0,w2d[0][0], fma2(h1,w2d[1][0], fma2(h2,w2d[2][0], fma2(h3,w2d[3][0], bb2[0]))));
        v2f l1 = fma2(h0,w2d[0][1], fma2(h1,w2d[1][1], fma2(h2,w2d[2][1], fma2(h3,w2d[3][1], bb2[1]))));
        v2f l2 = fma2(h0,w2d[0][2], fma2(h1,w2d[1][2], fma2(h2,w2d[2][2], fma2(h3,w2d[3][2], bb2[2]))));
        v2f e0 = exp2v(l0);
        v2f e1 = exp2v(l1);
        v2f e2 = exp2v(l2);
        v2f den = (e0 + e1) + (e2 + vOne);
        v2f num = fma2(e0, a0, fma2(e1, a1, fma2(e2, a2, x)));
        v2f o = num * rcpv(den);

        op[(size_t)(2*it)   * sN] = o.x;
        op[(size_t)(2*it+1) * sN] = o.y;
    }
}

extern "C" void kernel_launch(void* const* d_in, const int* in_sizes, int n_in,
                              void* d_out, int out_size, void* d_ws, size_t ws_size,
                              hipStream_t stream) {
    const float* s  = (const float*)d_in[0];
    const float* W1 = (const float*)d_in[1];
    const float* b1 = (const float*)d_in[2];
    const float* W2 = (const float*)d_in[3];
    const float* b2 = (const float*)d_in[4];
    float* out = (float*)d_out;

    const int K = 4;
    const int N = in_sizes[2] / K;       // b1 is N*K
    const int B = in_sizes[0] / N;       // s is B*N

    dim3 grid(N / 256, B / 8);
    gatemix_kernel<<<grid, 256, 0, stream>>>(s, W1, b1, W2, b2, out, B, N);
}